// Round 6
// baseline (4659.311 us; speedup 1.0000x reference)
//
#include <hip/hip_runtime.h>
#include <math.h>

typedef short v8s __attribute__((ext_vector_type(8)));
typedef float v4f __attribute__((ext_vector_type(4)));
typedef unsigned int v4u __attribute__((ext_vector_type(4)));
typedef unsigned short us;
typedef unsigned int uu;

#define MFMA16(a,b,c) __builtin_amdgcn_mfma_f32_16x16x32_bf16((a),(b),(c),0,0,0)

// ---------------- workspace layout (fragment-linear, permuted-k) ----------
// Permutation (chunk t): slot (g,i) holds logical k = 32t + 16*(i>>2) + 4g + (i&3).
// This makes layer N's D registers repack in-lane into layer N+1's B-fragment.
// w3f: [t 7][nt3 13][lane 64][i 8]   A: j=16nt3+(l&15), k=perm(t,g,i)
// w2f: [nt 13][lane 64][i 8]         A: j=16nt+(l&15),  k=8g+i      (standard)
// w4f: [t*2+jt 14][lane 64][i 8]     A: j=16jt+(l&15),  k=perm(t,g,i)
#define W3F_ELEMS (7*13*512)
#define W2F_ELEMS (13*512)
#define W4F_ELEMS (14*512)
#define CHUNK_E   (13*512)
#define OFF_W3F 0
#define OFF_W2F (OFF_W3F + W3F_ELEMS*2)
#define OFF_W4F (OFF_W2F + W2F_ELEMS*2)
#define OFF_B2B (OFF_W4F + W4F_ELEMS*2)
#define OFF_B3B (OFF_B2B + 208*4)
#define OFF_B4B (OFF_B3B + 224*4)
#define OFF_W5B (OFF_B4B + 32*4)
#define OFF_W1P (OFF_W5B + 32*4)   // [96] f32: w1x[32] | w1y[32] | b1p[32]

__device__ __forceinline__ us f2bf(float f) {
    union { float f; unsigned int u; } v; v.f = f;
    unsigned int u = v.u + 0x7FFFu + ((v.u >> 16) & 1u);   // RNE
    return (us)(u >> 16);
}
__device__ __forceinline__ uu pack2bf(float a, float b) {
    return (uu)f2bf(a) | ((uu)f2bf(b) << 16);
}

// ---------------- prep: fp32 weights -> bf16 fragment layout in ws --------
__global__ void prep_kernel(const float* __restrict__ w1, const float* __restrict__ b1,
                            const float* __restrict__ w2, const float* __restrict__ w3,
                            const float* __restrict__ w4, const float* __restrict__ b2,
                            const float* __restrict__ b3, const float* __restrict__ b4,
                            const float* __restrict__ w5, char* __restrict__ ws) {
    us* w3f = (us*)(ws + OFF_W3F);
    us* w2f = (us*)(ws + OFF_W2F);
    us* w4f = (us*)(ws + OFF_W4F);
    float* b2b = (float*)(ws + OFF_B2B);
    float* b3b = (float*)(ws + OFF_B3B);
    float* b4b = (float*)(ws + OFF_B4B);
    float* w5b = (float*)(ws + OFF_W5B);
    float* w1p = (float*)(ws + OFF_W1P);

    const int gid = blockIdx.x * blockDim.x + threadIdx.x;
    const int stride = gridDim.x * blockDim.x;

    for (int idx = gid; idx < W3F_ELEMS; idx += stride) {
        int i = idx & 7, lane = (idx >> 3) & 63, f = idx >> 9;
        int nt3 = f % 13, t = f / 13;
        int c = lane & 15, g = lane >> 4;
        int j = 16*nt3 + c;
        int k = 32*t + 16*(i >> 2) + 4*g + (i & 3);     // permuted-k
        w3f[idx] = f2bf((j < 200 && k < 200) ? w3[j*200 + k] : 0.f);
    }
    for (int idx = gid; idx < W2F_ELEMS; idx += stride) {
        int i = idx & 7, lane = (idx >> 3) & 63, nt = idx >> 9;
        int j = 16*nt + (lane & 15), k = 8*(lane >> 4) + i;   // standard k
        w2f[idx] = f2bf((j < 200 && k < 20) ? w2[j*20 + k] : 0.f);
    }
    for (int idx = gid; idx < W4F_ELEMS; idx += stride) {
        int i = idx & 7, lane = (idx >> 3) & 63, f = idx >> 9;
        int t = f >> 1, jt = f & 1;
        int c = lane & 15, g = lane >> 4;
        int j = 16*jt + c;
        int k = 32*t + 16*(i >> 2) + 4*g + (i & 3);     // permuted-k (matches b4f)
        w4f[idx] = f2bf((j < 20 && k < 200) ? w4[j*200 + k] : 0.f);
    }
    for (int i = gid; i < 208; i += stride) b2b[i] = (i < 200) ? b2[i] : 0.f;
    for (int i = gid; i < 224; i += stride) b3b[i] = (i < 200) ? b3[i] : 0.f;
    for (int i = gid; i < 32;  i += stride) b4b[i] = (i < 20) ? b4[i] : 0.f;
    for (int i = gid; i < 32;  i += stride) w5b[i] = (i < 20) ? w5[i] : 0.f;
    for (int i = gid; i < 96;  i += stride) {
        int q = i >> 5, r = i & 31;
        float v = 0.f;
        if (r < 20) v = (q == 0) ? w1[2*r] : (q == 1) ? w1[2*r + 1] : b1[r];
        w1p[i] = v;
    }
}

// ---------------- fused main kernel ----------------
// Block = 4 batch rows x 64 e = 256 MLP rows, 512 thr = 8 waves.
// Wave wv owns rows 32wv..32wv+31 (tiles m=0,1). All activations in registers;
// LDS only for the w3 chunk double-buffer + xbuf. ~28.7 KB -> 3-4 blocks/CU.
__global__ __launch_bounds__(512, 6) void fused_kernel(
    const int* __restrict__ user_idxs, const int* __restrict__ item_idxs,
    const int* __restrict__ uidx, const int* __restrict__ iidx,
    const float* __restrict__ uemb, const float* __restrict__ iemb,
    const float* __restrict__ b5p, const char* __restrict__ ws,
    float* __restrict__ out, int B)
{
    __shared__ us wstage[2][CHUNK_E];   // 26624 B : w3 chunk double buffer
    __shared__ float xbuf[8][64];       //  2048 B : gather sums; later mbuf

    const int tid  = (int)threadIdx.x;
    const int lane = tid & 63;
    const int wv   = __builtin_amdgcn_readfirstlane(tid >> 6);
    const int bbase = blockIdx.x << 2;
    const int c = lane & 15;
    const int g = lane >> 4;

    const us* w3f = (const us*)(ws + OFF_W3F);
    const us* w2f = (const us*)(ws + OFF_W2F);
    const us* w4f = (const us*)(ws + OFF_W4F);
    const float* b2b = (const float*)(ws + OFF_B2B);
    const float* b3b = (const float*)(ws + OFF_B3B);
    const float* b4b = (const float*)(ws + OFF_B4B);
    const float* w5b = (const float*)(ws + OFF_W5B);
    const float* w1p = (const float*)(ws + OFF_W1P);

    // ---- issue long-latency loads early: w3 chunk0 + w2 frags + w1 pack ---
    v8s st0 = *(const v8s*)(w3f + tid*8);
    v8s st1 = {};
    if (tid < 320) st1 = *(const v8s*)(w3f + (512 + tid)*8);

    v8s af2[13];
    #pragma unroll
    for (int nt = 0; nt < 13; ++nt)
        af2[nt] = *(const v8s*)(w2f + (nt*64 + lane)*8);

    const float4 wx0 = *(const float4*)(w1p + 8*g);
    const float4 wx1 = *(const float4*)(w1p + 8*g + 4);
    const float4 wy0 = *(const float4*)(w1p + 32 + 8*g);
    const float4 wy1 = *(const float4*)(w1p + 32 + 8*g + 4);
    const float4 wb0 = *(const float4*)(w1p + 64 + 8*g);
    const float4 wb1 = *(const float4*)(w1p + 64 + 8*g + 4);

    // ---- Phase 1: gather-sum; wave -> (b_local = wv>>1, table = wv&1) ----
    {
        int b = bbase + (wv >> 1); if (b >= B) b = B - 1;
        const int*   ntab = (wv & 1) ? iidx : uidx;
        const float* emb  = (wv & 1) ? iemb : uemb;
        const int idx0 = (wv & 1) ? item_idxs[b] : user_idxs[b];
        const int* nrow = ntab + idx0 * 100;
        float a0=0.f,a1=0.f,a2=0.f,a3=0.f,a4=0.f,a5=0.f,a6=0.f,a7=0.f;
        #pragma unroll 4
        for (int k = 0; k < 96; k += 8) {
            int4 i0 = *(const int4*)(nrow + k);
            int4 i1 = *(const int4*)(nrow + k + 4);
            a0 += emb[(size_t)i0.x * 64 + lane];
            a1 += emb[(size_t)i0.y * 64 + lane];
            a2 += emb[(size_t)i0.z * 64 + lane];
            a3 += emb[(size_t)i0.w * 64 + lane];
            a4 += emb[(size_t)i1.x * 64 + lane];
            a5 += emb[(size_t)i1.y * 64 + lane];
            a6 += emb[(size_t)i1.z * 64 + lane];
            a7 += emb[(size_t)i1.w * 64 + lane];
        }
        int4 it = *(const int4*)(nrow + 96);
        a0 += emb[(size_t)it.x * 64 + lane];
        a1 += emb[(size_t)it.y * 64 + lane];
        a2 += emb[(size_t)it.z * 64 + lane];
        a3 += emb[(size_t)it.w * 64 + lane];
        xbuf[wv][lane] = ((a0+a4)+(a1+a5)) + ((a2+a6)+(a3+a7));
    }

    // ---- write w3 chunk0 to LDS, prefetch chunk1 (T14 pipeline) -----------
    {
        us* b0 = (us*)wstage[0];
        *(v8s*)(b0 + tid*8) = st0;
        if (tid < 320) *(v8s*)(b0 + (512 + tid)*8) = st1;
        const us* src = w3f + CHUNK_E;
        st0 = *(const v8s*)(src + tid*8);
        if (tid < 320) st1 = *(const v8s*)(src + (512 + tid)*8);
    }
    __syncthreads();   // xbuf + chunk0 ready

    // ---- Layer 1 (2->20): per-lane redundant, direct to B-frag regs -------
    v4u b1f[2];
    {
        const int bl2 = (wv >> 1) * 2;
        const int eb = 32*(wv & 1) + c;
        #pragma unroll
        for (int m = 0; m < 2; ++m) {
            const float xu = xbuf[bl2][eb + 16*m];
            const float xv = xbuf[bl2 + 1][eb + 16*m];
            float h0 = fmaxf(fmaf(xu, wx0.x, fmaf(xv, wy0.x, wb0.x)), 0.f);
            float h1 = fmaxf(fmaf(xu, wx0.y, fmaf(xv, wy0.y, wb0.y)), 0.f);
            float h2 = fmaxf(fmaf(xu, wx0.z, fmaf(xv, wy0.z, wb0.z)), 0.f);
            float h3 = fmaxf(fmaf(xu, wx0.w, fmaf(xv, wy0.w, wb0.w)), 0.f);
            float h4 = fmaxf(fmaf(xu, wx1.x, fmaf(xv, wy1.x, wb1.x)), 0.f);
            float h5 = fmaxf(fmaf(xu, wx1.y, fmaf(xv, wy1.y, wb1.y)), 0.f);
            float h6 = fmaxf(fmaf(xu, wx1.z, fmaf(xv, wy1.z, wb1.z)), 0.f);
            float h7 = fmaxf(fmaf(xu, wx1.w, fmaf(xv, wy1.w, wb1.w)), 0.f);
            b1f[m] = (v4u){ pack2bf(h0,h1), pack2bf(h2,h3),
                            pack2bf(h4,h5), pack2bf(h6,h7) };
        }
    }

    // ---- Layer 2 (20->200) MFMA + in-lane repack to layer-3 B-frags -------
    v4u b2f[2][7];
    #pragma unroll
    for (int m = 0; m < 2; ++m) {
        v8s bf1 = __builtin_bit_cast(v8s, b1f[m]);
        v4f a2[13];
        #pragma unroll
        for (int nt = 0; nt < 13; ++nt) {
            v4f z = {0.f, 0.f, 0.f, 0.f};
            a2[nt] = MFMA16(af2[nt], bf1, z);
        }
        #pragma unroll
        for (int t = 0; t < 6; ++t) {
            float4 bv0 = *(const float4*)(b2b + 32*t + 4*g);
            float4 bv1 = *(const float4*)(b2b + 32*t + 16 + 4*g);
            b2f[m][t] = (v4u){
                pack2bf(fmaxf(a2[2*t][0]+bv0.x,0.f), fmaxf(a2[2*t][1]+bv0.y,0.f)),
                pack2bf(fmaxf(a2[2*t][2]+bv0.z,0.f), fmaxf(a2[2*t][3]+bv0.w,0.f)),
                pack2bf(fmaxf(a2[2*t+1][0]+bv1.x,0.f), fmaxf(a2[2*t+1][1]+bv1.y,0.f)),
                pack2bf(fmaxf(a2[2*t+1][2]+bv1.z,0.f), fmaxf(a2[2*t+1][3]+bv1.w,0.f)) };
        }
        {
            float4 bv0 = *(const float4*)(b2b + 192 + 4*g);
            b2f[m][6] = (v4u){
                pack2bf(fmaxf(a2[12][0]+bv0.x,0.f), fmaxf(a2[12][1]+bv0.y,0.f)),
                pack2bf(fmaxf(a2[12][2]+bv0.z,0.f), fmaxf(a2[12][3]+bv0.w,0.f)),
                0u, 0u };
        }
    }

    // ---- Layer 3 (200->200): 7 chunks, 1 barrier/chunk, B from registers --
    v4f acc3[2][13];
    #pragma unroll
    for (int m = 0; m < 2; ++m)
        #pragma unroll
        for (int nt = 0; nt < 13; ++nt) acc3[m][nt] = (v4f){0.f,0.f,0.f,0.f};

    #pragma unroll
    for (int ksc = 0; ksc < 7; ++ksc) {
        if (ksc < 6) {             // write staged chunk ksc+1; prefetch ksc+2
            us* nb = (us*)wstage[(ksc + 1) & 1];
            *(v8s*)(nb + tid*8) = st0;
            if (tid < 320) *(v8s*)(nb + (512 + tid)*8) = st1;
            if (ksc < 5) {
                const us* src = w3f + (ksc + 2)*CHUNK_E;
                st0 = *(const v8s*)(src + tid*8);
                if (tid < 320) st1 = *(const v8s*)(src + (512 + tid)*8);
            }
        }
        const us* wb = (const us*)wstage[ksc & 1];
        v8s bm0 = __builtin_bit_cast(v8s, b2f[0][ksc]);
        v8s bm1 = __builtin_bit_cast(v8s, b2f[1][ksc]);
        #pragma unroll
        for (int nt = 0; nt < 13; ++nt) {
            v8s af = *(const v8s*)(wb + (nt*64 + lane)*8);   // linear b128
            acc3[0][nt] = MFMA16(af, bm0, acc3[0][nt]);
            acc3[1][nt] = MFMA16(af, bm1, acc3[1][nt]);
        }
        __syncthreads();   // all waves done with wb; next buffer fully staged
    }

    // ---- Layer 3 epilogue: in-lane repack to layer-4 B-frags --------------
    v8s a4f[14];
    #pragma unroll
    for (int f = 0; f < 14; ++f)
        a4f[f] = *(const v8s*)(w4f + (f*64 + lane)*8);   // global, L2-resident

    v4u b4f[2][7];
    #pragma unroll
    for (int m = 0; m < 2; ++m) {
        #pragma unroll
        for (int t = 0; t < 6; ++t) {
            float4 bv0 = *(const float4*)(b3b + 32*t + 4*g);
            float4 bv1 = *(const float4*)(b3b + 32*t + 16 + 4*g);
            b4f[m][t] = (v4u){
                pack2bf(fmaxf(acc3[m][2*t][0]+bv0.x,0.f), fmaxf(acc3[m][2*t][1]+bv0.y,0.f)),
                pack2bf(fmaxf(acc3[m][2*t][2]+bv0.z,0.f), fmaxf(acc3[m][2*t][3]+bv0.w,0.f)),
                pack2bf(fmaxf(acc3[m][2*t+1][0]+bv1.x,0.f), fmaxf(acc3[m][2*t+1][1]+bv1.y,0.f)),
                pack2bf(fmaxf(acc3[m][2*t+1][2]+bv1.z,0.f), fmaxf(acc3[m][2*t+1][3]+bv1.w,0.f)) };
        }
        {
            float4 bv0 = *(const float4*)(b3b + 192 + 4*g);
            b4f[m][6] = (v4u){
                pack2bf(fmaxf(acc3[m][12][0]+bv0.x,0.f), fmaxf(acc3[m][12][1]+bv0.y,0.f)),
                pack2bf(fmaxf(acc3[m][12][2]+bv0.z,0.f), fmaxf(acc3[m][12][3]+bv0.w,0.f)),
                0u, 0u };
        }
    }

    // ---- Layer 4 (200->20): all-register MFMA ------------------------------
    v4f acc4[2][2];
    acc4[0][0] = (v4f){0,0,0,0}; acc4[0][1] = (v4f){0,0,0,0};
    acc4[1][0] = (v4f){0,0,0,0}; acc4[1][1] = (v4f){0,0,0,0};
    #pragma unroll
    for (int t = 0; t < 7; ++t) {
        v8s b0  = __builtin_bit_cast(v8s, b4f[0][t]);
        v8s b1v = __builtin_bit_cast(v8s, b4f[1][t]);
        acc4[0][0] = MFMA16(a4f[2*t],     b0,  acc4[0][0]);
        acc4[0][1] = MFMA16(a4f[2*t + 1], b0,  acc4[0][1]);
        acc4[1][0] = MFMA16(a4f[2*t],     b1v, acc4[1][0]);
        acc4[1][1] = MFMA16(a4f[2*t + 1], b1v, acc4[1][1]);
    }

    // ---- Layer 4 epilogue + Layer 5 (20->1) -> per-row value ---------------
    float* mbuf = (float*)xbuf;            // xbuf dead
    {
        float4 b4lo = *(const float4*)(b4b + 4*g);
        float4 b4hi = *(const float4*)(b4b + 16 + 4*g);
        float4 w5lo = *(const float4*)(w5b + 4*g);
        float4 w5hi = *(const float4*)(w5b + 16 + 4*g);
        #pragma unroll
        for (int m = 0; m < 2; ++m) {
            float sacc = 0.f;
            #pragma unroll
            for (int q = 0; q < 4; ++q) {
                float h0 = fmaxf(acc4[m][0][q] + ((const float*)&b4lo)[q], 0.f);
                float h1 = fmaxf(acc4[m][1][q] + ((const float*)&b4hi)[q], 0.f);
                sacc = fmaf(h0, ((const float*)&w5lo)[q],
                       fmaf(h1, ((const float*)&w5hi)[q], sacc));
            }
            sacc += __shfl_xor(sacc, 16);
            sacc += __shfl_xor(sacc, 32);            // sum over g-groups
            if (lane < 16)
                mbuf[16*(2*wv + m) + c] = sacc;
        }
    }
    __syncthreads();

    // ---- mean over E=64 + sigmoid ------------------------------------------
    if (tid < 256) {
        float v = mbuf[tid];
        #pragma unroll
        for (int off = 1; off < 64; off <<= 1) v += __shfl_xor(v, off);
        const int b = bbase + (tid >> 6);
        if ((tid & 63) == 0 && b < B) {
            const float mval = v * (1.0f / 64.0f) + b5p[0];
            out[b] = 1.0f / (1.0f + expf(-mval));
        }
    }
}

extern "C" void kernel_launch(void* const* d_in, const int* in_sizes, int n_in,
                              void* d_out, int out_size, void* d_ws, size_t ws_size,
                              hipStream_t stream) {
    const int*   user_idxs = (const int*)d_in[0];
    const int*   item_idxs = (const int*)d_in[1];
    const int*   uidx      = (const int*)d_in[2];
    const int*   iidx      = (const int*)d_in[3];
    const float* uemb      = (const float*)d_in[4];
    const float* iemb      = (const float*)d_in[5];
    const float* w1 = (const float*)d_in[6];
    const float* b1 = (const float*)d_in[7];
    const float* w2 = (const float*)d_in[8];
    const float* b2 = (const float*)d_in[9];
    const float* w3 = (const float*)d_in[10];
    const float* b3 = (const float*)d_in[11];
    const float* w4 = (const float*)d_in[12];
    const float* b4 = (const float*)d_in[13];
    const float* w5 = (const float*)d_in[14];
    const float* b5 = (const float*)d_in[15];
    float* out = (float*)d_out;
    char* ws = (char*)d_ws;

    const int B = in_sizes[0];

    hipLaunchKernelGGL(prep_kernel, dim3(256), dim3(256), 0, stream,
                       w1, b1, w2, w3, w4, b2, b3, b4, w5, ws);

    const int nblocks = (B + 3) >> 2;
    hipLaunchKernelGGL(fused_kernel, dim3(nblocks), dim3(512), 0, stream,
                       user_idxs, item_idxs, uidx, iidx, uemb, iemb,
                       b5, ws, out, B);
}

// Round 7
// 559.412 us; speedup vs baseline: 8.3289x; 8.3289x over previous
//
#include <hip/hip_runtime.h>
#include <math.h>

typedef short v8s __attribute__((ext_vector_type(8)));
typedef float v4f __attribute__((ext_vector_type(4)));
typedef unsigned int v4u __attribute__((ext_vector_type(4)));
typedef unsigned short us;
typedef unsigned int uu;

#define MFMA16(a,b,c) __builtin_amdgcn_mfma_f32_16x16x32_bf16((a),(b),(c),0,0,0)

// ---------------- workspace layout (fragment-linear, permuted-k) ----------
// Permutation (chunk t): slot (g,i) holds logical k = 32t + 16*(i>>2) + 4g + (i&3).
// This makes layer N's D registers repack in-lane into layer N+1's B-fragment.
// w3f: [t 7][nt3 13][lane 64][i 8]   A: j=16nt3+(l&15), k=perm(t,g,i)
// w2f: [nt 13][lane 64][i 8]         A: j=16nt+(l&15),  k=8g+i      (standard)
// w4f: [t*2+jt 14][lane 64][i 8]     A: j=16jt+(l&15),  k=perm(t,g,i)
#define W3F_ELEMS (7*13*512)
#define W2F_ELEMS (13*512)
#define W4F_ELEMS (14*512)
#define CHUNK_E   (13*512)
#define OFF_W3F 0
#define OFF_W2F (OFF_W3F + W3F_ELEMS*2)
#define OFF_W4F (OFF_W2F + W2F_ELEMS*2)
#define OFF_B2B (OFF_W4F + W4F_ELEMS*2)
#define OFF_B3B (OFF_B2B + 208*4)
#define OFF_B4B (OFF_B3B + 224*4)
#define OFF_W5B (OFF_B4B + 32*4)
#define OFF_W1P (OFF_W5B + 32*4)   // [96] f32: w1x[32] | w1y[32] | b1p[32]

__device__ __forceinline__ us f2bf(float f) {
    union { float f; unsigned int u; } v; v.f = f;
    unsigned int u = v.u + 0x7FFFu + ((v.u >> 16) & 1u);   // RNE
    return (us)(u >> 16);
}
__device__ __forceinline__ uu pack2bf(float a, float b) {
    return (uu)f2bf(a) | ((uu)f2bf(b) << 16);
}

// ---------------- prep: fp32 weights -> bf16 fragment layout in ws --------
__global__ void prep_kernel(const float* __restrict__ w1, const float* __restrict__ b1,
                            const float* __restrict__ w2, const float* __restrict__ w3,
                            const float* __restrict__ w4, const float* __restrict__ b2,
                            const float* __restrict__ b3, const float* __restrict__ b4,
                            const float* __restrict__ w5, char* __restrict__ ws) {
    us* w3f = (us*)(ws + OFF_W3F);
    us* w2f = (us*)(ws + OFF_W2F);
    us* w4f = (us*)(ws + OFF_W4F);
    float* b2b = (float*)(ws + OFF_B2B);
    float* b3b = (float*)(ws + OFF_B3B);
    float* b4b = (float*)(ws + OFF_B4B);
    float* w5b = (float*)(ws + OFF_W5B);
    float* w1p = (float*)(ws + OFF_W1P);

    const int gid = blockIdx.x * blockDim.x + threadIdx.x;
    const int stride = gridDim.x * blockDim.x;

    for (int idx = gid; idx < W3F_ELEMS; idx += stride) {
        int i = idx & 7, lane = (idx >> 3) & 63, f = idx >> 9;
        int nt3 = f % 13, t = f / 13;
        int c = lane & 15, g = lane >> 4;
        int j = 16*nt3 + c;
        int k = 32*t + 16*(i >> 2) + 4*g + (i & 3);     // permuted-k
        w3f[idx] = f2bf((j < 200 && k < 200) ? w3[j*200 + k] : 0.f);
    }
    for (int idx = gid; idx < W2F_ELEMS; idx += stride) {
        int i = idx & 7, lane = (idx >> 3) & 63, nt = idx >> 9;
        int j = 16*nt + (lane & 15), k = 8*(lane >> 4) + i;   // standard k
        w2f[idx] = f2bf((j < 200 && k < 20) ? w2[j*20 + k] : 0.f);
    }
    for (int idx = gid; idx < W4F_ELEMS; idx += stride) {
        int i = idx & 7, lane = (idx >> 3) & 63, f = idx >> 9;
        int t = f >> 1, jt = f & 1;
        int c = lane & 15, g = lane >> 4;
        int j = 16*jt + c;
        int k = 32*t + 16*(i >> 2) + 4*g + (i & 3);     // permuted-k (matches b4f)
        w4f[idx] = f2bf((j < 20 && k < 200) ? w4[j*200 + k] : 0.f);
    }
    for (int i = gid; i < 208; i += stride) b2b[i] = (i < 200) ? b2[i] : 0.f;
    for (int i = gid; i < 224; i += stride) b3b[i] = (i < 200) ? b3[i] : 0.f;
    for (int i = gid; i < 32;  i += stride) b4b[i] = (i < 20) ? b4[i] : 0.f;
    for (int i = gid; i < 32;  i += stride) w5b[i] = (i < 20) ? w5[i] : 0.f;
    for (int i = gid; i < 96;  i += stride) {
        int q = i >> 5, r = i & 31;
        float v = 0.f;
        if (r < 20) v = (q == 0) ? w1[2*r] : (q == 1) ? w1[2*r + 1] : b1[r];
        w1p[i] = v;
    }
}

// ---------------- fused main kernel ----------------
// Block = 4 batch rows x 64 e = 256 MLP rows, 512 thr = 8 waves.
// Wave wv owns rows 32wv..32wv+31 (tiles m=0,1). All activations in registers;
// LDS only for the w3 chunk double-buffer + xbuf (~28.7 KB).
// Register-resident state ~230 VGPR -> 2 waves/SIMD (launch_bounds(512,2));
// round-6's (512,6) forced a 40-VGPR allocation and spilled 11 GB to scratch.
__global__ __launch_bounds__(512, 2) void fused_kernel(
    const int* __restrict__ user_idxs, const int* __restrict__ item_idxs,
    const int* __restrict__ uidx, const int* __restrict__ iidx,
    const float* __restrict__ uemb, const float* __restrict__ iemb,
    const float* __restrict__ b5p, const char* __restrict__ ws,
    float* __restrict__ out, int B)
{
    __shared__ us wstage[2][CHUNK_E];   // 26624 B : w3 chunk double buffer
    __shared__ float xbuf[8][64];       //  2048 B : gather sums; later mbuf

    const int tid  = (int)threadIdx.x;
    const int lane = tid & 63;
    const int wv   = __builtin_amdgcn_readfirstlane(tid >> 6);
    const int bbase = blockIdx.x << 2;
    const int c = lane & 15;
    const int g = lane >> 4;

    const us* w3f = (const us*)(ws + OFF_W3F);
    const us* w2f = (const us*)(ws + OFF_W2F);
    const us* w4f = (const us*)(ws + OFF_W4F);
    const float* b2b = (const float*)(ws + OFF_B2B);
    const float* b3b = (const float*)(ws + OFF_B3B);
    const float* b4b = (const float*)(ws + OFF_B4B);
    const float* w5b = (const float*)(ws + OFF_W5B);
    const float* w1p = (const float*)(ws + OFF_W1P);

    // ---- issue long-latency loads early: w3 chunk0 + w2 frags + w1 pack ---
    v8s st0 = *(const v8s*)(w3f + tid*8);
    v8s st1 = {};
    if (tid < 320) st1 = *(const v8s*)(w3f + (512 + tid)*8);

    v8s af2[13];
    #pragma unroll
    for (int nt = 0; nt < 13; ++nt)
        af2[nt] = *(const v8s*)(w2f + (nt*64 + lane)*8);

    const float4 wx0 = *(const float4*)(w1p + 8*g);
    const float4 wx1 = *(const float4*)(w1p + 8*g + 4);
    const float4 wy0 = *(const float4*)(w1p + 32 + 8*g);
    const float4 wy1 = *(const float4*)(w1p + 32 + 8*g + 4);
    const float4 wb0 = *(const float4*)(w1p + 64 + 8*g);
    const float4 wb1 = *(const float4*)(w1p + 64 + 8*g + 4);

    // ---- Phase 1: gather-sum; wave -> (b_local = wv>>1, table = wv&1) ----
    {
        int b = bbase + (wv >> 1); if (b >= B) b = B - 1;
        const int*   ntab = (wv & 1) ? iidx : uidx;
        const float* emb  = (wv & 1) ? iemb : uemb;
        const int idx0 = (wv & 1) ? item_idxs[b] : user_idxs[b];
        const int* nrow = ntab + idx0 * 100;
        float a0=0.f,a1=0.f,a2=0.f,a3=0.f,a4=0.f,a5=0.f,a6=0.f,a7=0.f;
        #pragma unroll 4
        for (int k = 0; k < 96; k += 8) {
            int4 i0 = *(const int4*)(nrow + k);
            int4 i1 = *(const int4*)(nrow + k + 4);
            a0 += emb[(size_t)i0.x * 64 + lane];
            a1 += emb[(size_t)i0.y * 64 + lane];
            a2 += emb[(size_t)i0.z * 64 + lane];
            a3 += emb[(size_t)i0.w * 64 + lane];
            a4 += emb[(size_t)i1.x * 64 + lane];
            a5 += emb[(size_t)i1.y * 64 + lane];
            a6 += emb[(size_t)i1.z * 64 + lane];
            a7 += emb[(size_t)i1.w * 64 + lane];
        }
        int4 it = *(const int4*)(nrow + 96);
        a0 += emb[(size_t)it.x * 64 + lane];
        a1 += emb[(size_t)it.y * 64 + lane];
        a2 += emb[(size_t)it.z * 64 + lane];
        a3 += emb[(size_t)it.w * 64 + lane];
        xbuf[wv][lane] = ((a0+a4)+(a1+a5)) + ((a2+a6)+(a3+a7));
    }

    // ---- write w3 chunk0 to LDS, prefetch chunk1 (T14 pipeline) -----------
    {
        us* b0 = (us*)wstage[0];
        *(v8s*)(b0 + tid*8) = st0;
        if (tid < 320) *(v8s*)(b0 + (512 + tid)*8) = st1;
        const us* src = w3f + CHUNK_E;
        st0 = *(const v8s*)(src + tid*8);
        if (tid < 320) st1 = *(const v8s*)(src + (512 + tid)*8);
    }
    __syncthreads();   // xbuf + chunk0 ready

    // ---- Layer 1 (2->20): per-lane redundant, direct to B-frag regs -------
    v4u b1f[2];
    {
        const int bl2 = (wv >> 1) * 2;
        const int eb = 32*(wv & 1) + c;
        #pragma unroll
        for (int m = 0; m < 2; ++m) {
            const float xu = xbuf[bl2][eb + 16*m];
            const float xv = xbuf[bl2 + 1][eb + 16*m];
            float h0 = fmaxf(fmaf(xu, wx0.x, fmaf(xv, wy0.x, wb0.x)), 0.f);
            float h1 = fmaxf(fmaf(xu, wx0.y, fmaf(xv, wy0.y, wb0.y)), 0.f);
            float h2 = fmaxf(fmaf(xu, wx0.z, fmaf(xv, wy0.z, wb0.z)), 0.f);
            float h3 = fmaxf(fmaf(xu, wx0.w, fmaf(xv, wy0.w, wb0.w)), 0.f);
            float h4 = fmaxf(fmaf(xu, wx1.x, fmaf(xv, wy1.x, wb1.x)), 0.f);
            float h5 = fmaxf(fmaf(xu, wx1.y, fmaf(xv, wy1.y, wb1.y)), 0.f);
            float h6 = fmaxf(fmaf(xu, wx1.z, fmaf(xv, wy1.z, wb1.z)), 0.f);
            float h7 = fmaxf(fmaf(xu, wx1.w, fmaf(xv, wy1.w, wb1.w)), 0.f);
            b1f[m] = (v4u){ pack2bf(h0,h1), pack2bf(h2,h3),
                            pack2bf(h4,h5), pack2bf(h6,h7) };
        }
    }

    // ---- Layer 2 (20->200) MFMA + in-lane repack to layer-3 B-frags -------
    v4u b2f[2][7];
    #pragma unroll
    for (int m = 0; m < 2; ++m) {
        v8s bf1 = __builtin_bit_cast(v8s, b1f[m]);
        v4f a2[13];
        #pragma unroll
        for (int nt = 0; nt < 13; ++nt) {
            v4f z = {0.f, 0.f, 0.f, 0.f};
            a2[nt] = MFMA16(af2[nt], bf1, z);
        }
        #pragma unroll
        for (int t = 0; t < 6; ++t) {
            float4 bv0 = *(const float4*)(b2b + 32*t + 4*g);
            float4 bv1 = *(const float4*)(b2b + 32*t + 16 + 4*g);
            b2f[m][t] = (v4u){
                pack2bf(fmaxf(a2[2*t][0]+bv0.x,0.f), fmaxf(a2[2*t][1]+bv0.y,0.f)),
                pack2bf(fmaxf(a2[2*t][2]+bv0.z,0.f), fmaxf(a2[2*t][3]+bv0.w,0.f)),
                pack2bf(fmaxf(a2[2*t+1][0]+bv1.x,0.f), fmaxf(a2[2*t+1][1]+bv1.y,0.f)),
                pack2bf(fmaxf(a2[2*t+1][2]+bv1.z,0.f), fmaxf(a2[2*t+1][3]+bv1.w,0.f)) };
        }
        {
            float4 bv0 = *(const float4*)(b2b + 192 + 4*g);
            b2f[m][6] = (v4u){
                pack2bf(fmaxf(a2[12][0]+bv0.x,0.f), fmaxf(a2[12][1]+bv0.y,0.f)),
                pack2bf(fmaxf(a2[12][2]+bv0.z,0.f), fmaxf(a2[12][3]+bv0.w,0.f)),
                0u, 0u };
        }
    }

    // ---- Layer 3 (200->200): 7 chunks, 1 barrier/chunk, B from registers --
    v4f acc3[2][13];
    #pragma unroll
    for (int m = 0; m < 2; ++m)
        #pragma unroll
        for (int nt = 0; nt < 13; ++nt) acc3[m][nt] = (v4f){0.f,0.f,0.f,0.f};

    #pragma unroll
    for (int ksc = 0; ksc < 7; ++ksc) {
        if (ksc < 6) {             // write staged chunk ksc+1; prefetch ksc+2
            us* nb = (us*)wstage[(ksc + 1) & 1];
            *(v8s*)(nb + tid*8) = st0;
            if (tid < 320) *(v8s*)(nb + (512 + tid)*8) = st1;
            if (ksc < 5) {
                const us* src = w3f + (ksc + 2)*CHUNK_E;
                st0 = *(const v8s*)(src + tid*8);
                if (tid < 320) st1 = *(const v8s*)(src + (512 + tid)*8);
            }
        }
        const us* wb = (const us*)wstage[ksc & 1];
        v8s bm0 = __builtin_bit_cast(v8s, b2f[0][ksc]);
        v8s bm1 = __builtin_bit_cast(v8s, b2f[1][ksc]);
        #pragma unroll
        for (int nt = 0; nt < 13; ++nt) {
            v8s af = *(const v8s*)(wb + (nt*64 + lane)*8);   // linear b128
            acc3[0][nt] = MFMA16(af, bm0, acc3[0][nt]);
            acc3[1][nt] = MFMA16(af, bm1, acc3[1][nt]);
        }
        __syncthreads();   // all waves done with wb; next buffer fully staged
    }

    // ---- Layer 3 epilogue fused into Layer 4 (200->20): build each b4-frag
    //      just before its MFMA (keeps b4 live state at 8 regs, acc3 dies
    //      progressively); a4f weight frags software-pipelined by 1 ---------
    v4f acc4[2][2];
    acc4[0][0] = (v4f){0,0,0,0}; acc4[0][1] = (v4f){0,0,0,0};
    acc4[1][0] = (v4f){0,0,0,0}; acc4[1][1] = (v4f){0,0,0,0};

    v8s a40 = *(const v8s*)(w4f + 0*512 + lane*8);
    v8s a41 = *(const v8s*)(w4f + 1*512 + lane*8);

    #pragma unroll
    for (int t = 0; t < 7; ++t) {
        v8s na0, na1;
        if (t < 6) {
            na0 = *(const v8s*)(w4f + ((t+1)*2 + 0)*512 + lane*8);
            na1 = *(const v8s*)(w4f + ((t+1)*2 + 1)*512 + lane*8);
        }
        #pragma unroll
        for (int m = 0; m < 2; ++m) {
            v4u bf;
            if (t < 6) {
                float4 bv0 = *(const float4*)(b3b + 32*t + 4*g);
                float4 bv1 = *(const float4*)(b3b + 32*t + 16 + 4*g);
                bf = (v4u){
                    pack2bf(fmaxf(acc3[m][2*t][0]+bv0.x,0.f), fmaxf(acc3[m][2*t][1]+bv0.y,0.f)),
                    pack2bf(fmaxf(acc3[m][2*t][2]+bv0.z,0.f), fmaxf(acc3[m][2*t][3]+bv0.w,0.f)),
                    pack2bf(fmaxf(acc3[m][2*t+1][0]+bv1.x,0.f), fmaxf(acc3[m][2*t+1][1]+bv1.y,0.f)),
                    pack2bf(fmaxf(acc3[m][2*t+1][2]+bv1.z,0.f), fmaxf(acc3[m][2*t+1][3]+bv1.w,0.f)) };
            } else {
                float4 bv0 = *(const float4*)(b3b + 192 + 4*g);
                bf = (v4u){
                    pack2bf(fmaxf(acc3[m][12][0]+bv0.x,0.f), fmaxf(acc3[m][12][1]+bv0.y,0.f)),
                    pack2bf(fmaxf(acc3[m][12][2]+bv0.z,0.f), fmaxf(acc3[m][12][3]+bv0.w,0.f)),
                    0u, 0u };
            }
            v8s bb = __builtin_bit_cast(v8s, bf);
            acc4[m][0] = MFMA16(a40, bb, acc4[m][0]);
            acc4[m][1] = MFMA16(a41, bb, acc4[m][1]);
        }
        if (t < 6) { a40 = na0; a41 = na1; }
    }

    // ---- Layer 4 epilogue + Layer 5 (20->1) -> per-row value ---------------
    float* mbuf = (float*)xbuf;            // xbuf dead
    {
        float4 b4lo = *(const float4*)(b4b + 4*g);
        float4 b4hi = *(const float4*)(b4b + 16 + 4*g);
        float4 w5lo = *(const float4*)(w5b + 4*g);
        float4 w5hi = *(const float4*)(w5b + 16 + 4*g);
        #pragma unroll
        for (int m = 0; m < 2; ++m) {
            float sacc = 0.f;
            #pragma unroll
            for (int q = 0; q < 4; ++q) {
                float h0 = fmaxf(acc4[m][0][q] + ((const float*)&b4lo)[q], 0.f);
                float h1 = fmaxf(acc4[m][1][q] + ((const float*)&b4hi)[q], 0.f);
                sacc = fmaf(h0, ((const float*)&w5lo)[q],
                       fmaf(h1, ((const float*)&w5hi)[q], sacc));
            }
            sacc += __shfl_xor(sacc, 16);
            sacc += __shfl_xor(sacc, 32);            // sum over g-groups
            if (lane < 16)
                mbuf[16*(2*wv + m) + c] = sacc;
        }
    }
    __syncthreads();

    // ---- mean over E=64 + sigmoid ------------------------------------------
    if (tid < 256) {
        float v = mbuf[tid];
        #pragma unroll
        for (int off = 1; off < 64; off <<= 1) v += __shfl_xor(v, off);
        const int b = bbase + (tid >> 6);
        if ((tid & 63) == 0 && b < B) {
            const float mval = v * (1.0f / 64.0f) + b5p[0];
            out[b] = 1.0f / (1.0f + expf(-mval));
        }
    }
}

extern "C" void kernel_launch(void* const* d_in, const int* in_sizes, int n_in,
                              void* d_out, int out_size, void* d_ws, size_t ws_size,
                              hipStream_t stream) {
    const int*   user_idxs = (const int*)d_in[0];
    const int*   item_idxs = (const int*)d_in[1];
    const int*   uidx      = (const int*)d_in[2];
    const int*   iidx      = (const int*)d_in[3];
    const float* uemb      = (const float*)d_in[4];
    const float* iemb      = (const float*)d_in[5];
    const float* w1 = (const float*)d_in[6];
    const float* b1 = (const float*)d_in[7];
    const float* w2 = (const float*)d_in[8];
    const float* b2 = (const float*)d_in[9];
    const float* w3 = (const float*)d_in[10];
    const float* b3 = (const float*)d_in[11];
    const float* w4 = (const float*)d_in[12];
    const float* b4 = (const float*)d_in[13];
    const float* w5 = (const float*)d_in[14];
    const float* b5 = (const float*)d_in[15];
    float* out = (float*)d_out;
    char* ws = (char*)d_ws;

    const int B = in_sizes[0];

    hipLaunchKernelGGL(prep_kernel, dim3(256), dim3(256), 0, stream,
                       w1, b1, w2, w3, w4, b2, b3, b4, w5, ws);

    const int nblocks = (B + 3) >> 2;
    hipLaunchKernelGGL(fused_kernel, dim3(nblocks), dim3(512), 0, stream,
                       user_idxs, item_idxs, uidx, iidx, uemb, iemb,
                       b5, ws, out, B);
}